// Round 10
// baseline (140.551 us; speedup 1.0000x reference)
//
#include <hip/hip_runtime.h>

constexpr int NS = 64;          // samples
constexpr int NA = 64;          // agents per sample
constexpr int NN = NS * NA;     // 4096 nodes
constexpr int FD = 128;         // feature dim
constexpr int ZD = 2 * FD + 2;  // 258
constexpr int FS = 16;          // feature-slice width per block
constexpr int NB = NS * (FD / FS); // 512 blocks = (sample, f-slice)
constexpr int NT = 512;         // threads per block
constexpr int XPAD = 132;       // xs row stride: 528B = 33*16 (float4-aligned), +4 bank skew
constexpr float BN_EPS = 1e-5f;
constexpr float L2E = 1.44269504088896f;
constexpr float LN2 = 0.69314718055995f;

// Pack both layers' weights into PK[k][f] = {Wf[f][k], Wf[f][k+128],
// Ws[f][k], Ws[f][k+128]} (R2-proven pattern). Tiny kernel (~2us); removing
// wlds from BOTH layer kernels drops their LDS 73.5->41.5 KB => 3 blocks/CU
// (24 waves/CU, +50% latency hiding) — the occupancy experiment.
__global__ __launch_bounds__(256) void pack_kernel(
    const float* __restrict__ Wf1, const float* __restrict__ Ws1, float4* __restrict__ PK1,
    const float* __restrict__ Wf2, const float* __restrict__ Ws2, float4* __restrict__ PK2)
{
    int gidx = blockIdx.x * 256 + threadIdx.x;   // 0 .. 32767
    const float* Wf; const float* Ws; float4* PK; int i;
    if (gidx < FD * FD) { Wf = Wf1; Ws = Ws1; PK = PK1; i = gidx; }
    else                { Wf = Wf2; Ws = Ws2; PK = PK2; i = gidx - FD * FD; }
    int k = i >> 7, f = i & 127;
    PK[i] = make_float4(Wf[f * ZD + k], Wf[f * ZD + FD + k],
                        Ws[f * ZD + k], Ws[f * ZD + FD + k]);
}

// Post-GEMM tail: bias/centers fold, exp-domain transform, Q -> LDS tile,
// edge aggregation, BN partial stores (unchanged, R3..R9-proven).
__device__ __forceinline__ void layer_tail(
    float aPf0, float aQf0, float aPs0, float aQs0,
    float aPf1, float aQf1, float aPs1, float aQs1,
    const float2* cs, float2 (*q)[FS],
    const float* __restrict__ Wf, const float* __restrict__ Ws,
    const float* __restrict__ bf, const float* __restrict__ bs,
    int tid, int fl, int ig, int f, int s, int fq, int base,
    float* __restrict__ agg, float* __restrict__ pS, float* __restrict__ pSS)
{
    float we0 = Wf[f*ZD + 2*FD], we1 = Wf[f*ZD + 2*FD + 1];
    float ws0 = Ws[f*ZD + 2*FD], ws1 = Ws[f*ZD + 2*FD + 1];
    float bfv = bf[f], bsv = bs[f];
    float2 c0 = cs[ig], c1 = cs[ig + 32];
    float cf0 = c0.x*we0 + c0.y*we1, cg0 = c0.x*ws0 + c0.y*ws1;
    float cf1 = c1.x*we0 + c1.y*we1, cg1 = c1.x*ws0 + c1.y*ws1;
    float Pf0 = aPf0 + cf0 + bfv, Ps0 = aPs0 + cg0 + bsv;
    float Pf1 = aPf1 + cf1 + bfv, Ps1 = aPs1 + cg1 + bsv;
    float Qf0 = aQf0 - cf0,       Qs0 = aQs0 - cg0;
    float Qf1 = aQf1 - cf1,       Qs1 = aQs1 - cg1;
    // exp-domain: sigma = rcp(1 + e^{-P}e^{-Q}), softplus*log2e = log2(1 + e^{Ps}e^{Qs})
    float2 p0 = make_float2(__builtin_amdgcn_exp2f(-Pf0*L2E), __builtin_amdgcn_exp2f(Ps0*L2E));
    float2 p1 = make_float2(__builtin_amdgcn_exp2f(-Pf1*L2E), __builtin_amdgcn_exp2f(Ps1*L2E));
    q[ig][fl]    = make_float2(__builtin_amdgcn_exp2f(-Qf0*L2E), __builtin_amdgcn_exp2f(Qs0*L2E));
    q[ig+32][fl] = make_float2(__builtin_amdgcn_exp2f(-Qf1*L2E), __builtin_amdgcn_exp2f(Qs1*L2E));
    __syncthreads();

    // ---- edge aggregation: i in {ig, ig+32}, all 64 j, dual chains ----
    float a0=0.f, a1=0.f, b0=0.f, b1=0.f;
    #pragma unroll 4
    for (int j = 0; j < NA; j += 2) {
        float2 qa = q[j][fl];            // same-address bcast per lane-group: free
        float2 qb = q[j+1][fl];
        a0 = fmaf(__builtin_amdgcn_rcpf(1.0f + p0.x*qa.x),
                  __builtin_amdgcn_logf(1.0f + p0.y*qa.y), a0);
        b0 = fmaf(__builtin_amdgcn_rcpf(1.0f + p1.x*qa.x),
                  __builtin_amdgcn_logf(1.0f + p1.y*qa.y), b0);
        a1 = fmaf(__builtin_amdgcn_rcpf(1.0f + p0.x*qb.x),
                  __builtin_amdgcn_logf(1.0f + p0.y*qb.y), a1);
        b1 = fmaf(__builtin_amdgcn_rcpf(1.0f + p1.x*qb.x),
                  __builtin_amdgcn_logf(1.0f + p1.y*qb.y), b1);
    }
    float aA = a0 + a1, aB = b0 + b1;
    {   // remove self-loop terms (j == i)
        float2 qv0 = q[ig][fl];
        aA -= __builtin_amdgcn_rcpf(1.0f + p0.x*qv0.x) *
              __builtin_amdgcn_logf(1.0f + p0.y*qv0.y);
        float2 qv1 = q[ig+32][fl];
        aB -= __builtin_amdgcn_rcpf(1.0f + p1.x*qv1.x) *
              __builtin_amdgcn_logf(1.0f + p1.y*qv1.y);
    }
    aA *= LN2; aB *= LN2;               // log2 -> ln once, outside the sum
    agg[(base + ig) * FD + f]      = aA;
    agg[(base + ig + 32) * FD + f] = aB;

    // ---- BN partial stats: reduce 64 i per f in-block, plain stores ----
    __syncthreads();                    // all q reads done; alias as scratch
    float* sm = (float*)q;              // 2048 floats available, need 1024
    sm[tid]      = aA + aB;
    sm[NT + tid] = aA*aA + aB*aB;
    __syncthreads();
    if (tid < FS) {
        float sv = 0.f, qv = 0.f;
        #pragma unroll
        for (int r = 0; r < 32; ++r) {
            sv += sm[r * FS + tid];
            qv += sm[NT + r * FS + tid];
        }
        pS [s * FD + fq * FS + tid] = sv;   // distinct slot per block: no atomics
        pSS[s * FD + fq * FS + tid] = qv;
    }
}

// 8-FMA x 4k GEMM step (identical FMA order across all rounds).
#define GEMM_STEP(xv, wv) \
    aPf0 = fmaf(x0.xv, wv.x, aPf0); aQf0 = fmaf(x0.xv, wv.y, aQf0); \
    aPs0 = fmaf(x0.xv, wv.z, aPs0); aQs0 = fmaf(x0.xv, wv.w, aQs0); \
    aPf1 = fmaf(x1.xv, wv.x, aPf1); aQf1 = fmaf(x1.xv, wv.y, aQf1); \
    aPs1 = fmaf(x1.xv, wv.z, aPs1); aQs1 = fmaf(x1.xv, wv.w, aQs1);

// GEMM: x float4 from LDS, W float4 from packed PK via VMEM (R9-layer2-
// verified loop; 256B/wave contiguous, XCD-L2 hot).
#define GEMM_LOOP(PKp) \
    float aPf0=0.f,aQf0=0.f,aPs0=0.f,aQs0=0.f; \
    float aPf1=0.f,aQf1=0.f,aPs1=0.f,aQs1=0.f; \
    { const float4* Wp = (PKp) + f; \
      _Pragma("unroll 2") \
      for (int k = 0; k < FD; k += 4) { \
        float4 x0 = *(const float4*)&xs[ig][k]; \
        float4 x1 = *(const float4*)&xs[ig + 32][k]; \
        float4 w0 = Wp[(k + 0) * FD]; \
        float4 w1 = Wp[(k + 1) * FD]; \
        float4 w2 = Wp[(k + 2) * FD]; \
        float4 w3 = Wp[(k + 3) * FD]; \
        GEMM_STEP(x, w0) GEMM_STEP(y, w1) GEMM_STEP(z, w2) GEMM_STEP(w, w3) \
      } }

// Layer 1 (slim): LDS = xs 33 + q 8 + cs 0.5 = 41.5 KB -> 3 blocks/CU,
// launch_bounds(512,6) caps VGPR<=85 -> 24 waves/CU.
__global__ __launch_bounds__(NT, 6) void layer1_kernel(
    const float* __restrict__ X0, const float* __restrict__ C,
    const float4* __restrict__ PK,
    const float* __restrict__ Wf, const float* __restrict__ Ws,
    const float* __restrict__ bf, const float* __restrict__ bs,
    float* __restrict__ agg, float* __restrict__ pS, float* __restrict__ pSS)
{
    __shared__ __align__(16) float xs[NA][XPAD];  // 33 KB
    __shared__ float2 q[NA][FS];                  //  8 KB
    __shared__ float2 cs[NA];                     // 0.5 KB
    int tid = threadIdx.x, bid = blockIdx.x;
    int s = bid & (NS - 1), fq = bid >> 6;
    int base = s * NA;
    const float4* Xv = (const float4*)(X0 + base * FD);
    for (int idx = tid; idx < NA * FD / 4; idx += NT) {
        int n = idx >> 5, k4 = idx & 31;
        *(float4*)&xs[n][k4 * 4] = Xv[idx];
    }
    if (tid < NA) cs[tid] = ((const float2*)C)[base + tid];
    __syncthreads();
    const int fl = tid & (FS - 1), ig = tid >> 4;
    const int f  = fq * FS + fl;
    GEMM_LOOP(PK)
    layer_tail(aPf0,aQf0,aPs0,aQs0, aPf1,aQf1,aPs1,aQs1,
               cs, q, Wf, Ws, bf, bs, tid, fl, ig, f, s, fq, base, agg, pS, pSS);
}

// Layer 2 (slim): stats1 reduce + x1 = relu(BN1(agg1)+x0) -> LDS + global,
// then GEMM (PK2 via VMEM) + edge. LDS 42.5 KB -> 3 blocks/CU.
__global__ __launch_bounds__(NT, 6) void layer2_kernel(
    const float* __restrict__ X0, const float* __restrict__ agg1,
    const float* __restrict__ C,
    const float* __restrict__ pS1, const float* __restrict__ pSS1,
    const float* __restrict__ g1, const float* __restrict__ be1,
    const float4* __restrict__ PK,
    const float* __restrict__ Wf, const float* __restrict__ Ws,
    const float* __restrict__ bf, const float* __restrict__ bs,
    float* __restrict__ x1, float* __restrict__ agg2,
    float* __restrict__ pS2, float* __restrict__ pSS2)
{
    __shared__ __align__(16) float xs[NA][XPAD];  // 33 KB
    __shared__ float2 q[NA][FS];                  //  8 KB
    __shared__ float2 cs[NA];
    __shared__ float bnsc[FD], bnsh[FD];          // (42.5 KB total)
    int tid = threadIdx.x, bid = blockIdx.x;
    int s = bid & (NS - 1), fq = bid >> 6;
    int base = s * NA;
    {   // stats1 partial reduce, all 512 threads (4 sample-groups x 128 f)
        int fr = tid & (FD - 1), sq = tid >> 7;
        float sv = 0.f, qv = 0.f;
        #pragma unroll
        for (int s2 = 0; s2 < NS / 4; ++s2) {
            int si = sq * (NS / 4) + s2;
            sv += pS1[si * FD + fr];
            qv += pSS1[si * FD + fr];
        }
        float* sm = (float*)q;          // scratch (q dead until tail)
        sm[tid] = sv;
        sm[NT + tid] = qv;
    }
    if (tid < NA) cs[tid] = ((const float2*)C)[base + tid];
    __syncthreads();
    if (tid < FD) {
        const float* sm = (const float*)q;
        float sv = sm[tid] + sm[FD + tid] + sm[2*FD + tid] + sm[3*FD + tid];
        float qv = sm[NT + tid] + sm[NT + FD + tid] + sm[NT + 2*FD + tid] + sm[NT + 3*FD + tid];
        float m  = sv * (1.0f / NN);
        float v  = qv * (1.0f / NN) - m * m;
        float sc = g1[tid] * rsqrtf(v + BN_EPS);
        bnsc[tid] = sc;
        bnsh[tid] = be1[tid] - m * sc;
    }
    __syncthreads();
    const float4* Xv  = (const float4*)(X0 + base * FD);
    const float4* Av  = (const float4*)(agg1 + base * FD);
    float4*       X1v = (float4*)(x1 + base * FD);
    for (int idx = tid; idx < NA * FD / 4; idx += NT) {
        int n = idx >> 5, k4 = (idx & 31) * 4;
        float4 x = Xv[idx], a = Av[idx];
        float4 r;
        r.x = fmaxf(fmaf(a.x, bnsc[k4 + 0], bnsh[k4 + 0]) + x.x, 0.0f);
        r.y = fmaxf(fmaf(a.y, bnsc[k4 + 1], bnsh[k4 + 1]) + x.y, 0.0f);
        r.z = fmaxf(fmaf(a.z, bnsc[k4 + 2], bnsh[k4 + 2]) + x.z, 0.0f);
        r.w = fmaxf(fmaf(a.w, bnsc[k4 + 3], bnsh[k4 + 3]) + x.w, 0.0f);
        *(float4*)&xs[n][k4] = r;
        X1v[idx] = r;                   // x1 for the epilogue kernel
    }
    __syncthreads();
    const int fl = tid & (FS - 1), ig = tid >> 4;
    const int f  = fq * FS + fl;
    GEMM_LOOP(PK)
    layer_tail(aPf0,aQf0,aPs0,aQs0, aPf1,aQf1,aPs1,aQs1,
               cs, q, Wf, Ws, bf, bs, tid, fl, ig, f, s, fq, base, agg2, pS2, pSS2);
}

// Epilogue: parallel stats2 reduce per block, out = relu(BN2(agg2) + x1).
__global__ __launch_bounds__(256) void out_kernel(
    const float4* __restrict__ x1, const float4* __restrict__ agg2,
    const float* __restrict__ pS2, const float* __restrict__ pSS2,
    const float* __restrict__ g2, const float* __restrict__ be2,
    float4* __restrict__ out)
{
    __shared__ float sm[1024];
    __shared__ float sc[FD], sh[FD];
    int tid = threadIdx.x;
    {   // 256 threads = 128 f x 2 sample-halves
        int fr = tid & (FD - 1), sq = tid >> 7;
        float sv = 0.f, qv = 0.f;
        #pragma unroll
        for (int s2 = 0; s2 < NS / 2; ++s2) {
            int si = sq * (NS / 2) + s2;
            sv += pS2[si * FD + fr];
            qv += pSS2[si * FD + fr];
        }
        sm[tid] = sv;
        sm[512 + tid] = qv;
    }
    __syncthreads();
    if (tid < FD) {
        float sv = sm[tid] + sm[FD + tid];
        float qv = sm[512 + tid] + sm[512 + FD + tid];
        float m  = sv * (1.0f / NN);
        float v  = qv * (1.0f / NN) - m * m;
        float scl = g2[tid] * rsqrtf(v + BN_EPS);
        sc[tid] = scl;
        sh[tid] = be2[tid] - m * scl;
    }
    __syncthreads();
    int idx = blockIdx.x * 256 + tid;   // < NN*FD/4
    int f0 = (idx & 31) * 4;
    float4 xv = x1[idx], av = agg2[idx];
    float4 r;
    r.x = fmaxf(fmaf(av.x, sc[f0 + 0], sh[f0 + 0]) + xv.x, 0.0f);
    r.y = fmaxf(fmaf(av.y, sc[f0 + 1], sh[f0 + 1]) + xv.y, 0.0f);
    r.z = fmaxf(fmaf(av.z, sc[f0 + 2], sh[f0 + 2]) + xv.z, 0.0f);
    r.w = fmaxf(fmaf(av.w, sc[f0 + 3], sh[f0 + 3]) + xv.w, 0.0f);
    out[idx] = r;
}

extern "C" void kernel_launch(void* const* d_in, const int* in_sizes, int n_in,
                              void* d_out, int out_size, void* d_ws, size_t ws_size,
                              hipStream_t stream) {
    const float* gnn_in  = (const float*)d_in[0];
    const float* centers = (const float*)d_in[1];
    // d_in[2]=src, d_in[3]=dst: structure known (fully connected per sample) — unused
    const float* Wf1 = (const float*)d_in[4];
    const float* bf1 = (const float*)d_in[5];
    const float* Ws1 = (const float*)d_in[6];
    const float* bs1 = (const float*)d_in[7];
    const float* g1  = (const float*)d_in[8];
    const float* be1 = (const float*)d_in[9];
    const float* Wf2 = (const float*)d_in[10];
    const float* bf2 = (const float*)d_in[11];
    const float* Ws2 = (const float*)d_in[12];
    const float* bs2 = (const float*)d_in[13];
    const float* g2  = (const float*)d_in[14];
    const float* be2 = (const float*)d_in[15];

    char* ws = (char*)d_ws;
    float*  agg1 = (float*)(ws);                             // 2 MB
    float*  agg2 = (float*)(ws + (2 << 20));                 // 2 MB
    float*  x1   = (float*)(ws + (4 << 20));                 // 2 MB
    float*  p1S  = (float*)(ws + (6 << 20));                 // 32 KB
    float*  p1SS = (float*)(ws + (6 << 20) + (32 << 10));    // 32 KB
    float*  p2S  = (float*)(ws + (6 << 20) + (64 << 10));    // 32 KB
    float*  p2SS = (float*)(ws + (6 << 20) + (96 << 10));    // 32 KB
    float4* PK1  = (float4*)(ws + (6 << 20) + (128 << 10));  // 256 KB
    float4* PK2  = (float4*)(ws + (6 << 20) + (384 << 10));  // 256 KB

    pack_kernel<<<128, 256, 0, stream>>>(Wf1, Ws1, PK1, Wf2, Ws2, PK2);
    layer1_kernel<<<NB, NT, 0, stream>>>(gnn_in, centers, PK1, Wf1, Ws1, bf1, bs1,
                                         agg1, p1S, p1SS);
    layer2_kernel<<<NB, NT, 0, stream>>>(gnn_in, agg1, centers, p1S, p1SS, g1, be1,
                                         PK2, Wf2, Ws2, bf2, bs2,
                                         x1, agg2, p2S, p2SS);
    out_kernel<<<NN * FD / 4 / 256, 256, 0, stream>>>(
        (const float4*)x1, (const float4*)agg2, p2S, p2SS, g2, be2, (float4*)d_out);
}

// Round 11
// 129.210 us; speedup vs baseline: 1.0878x; 1.0878x over previous
//
#include <hip/hip_runtime.h>

constexpr int NS = 64;          // samples
constexpr int NA = 64;          // agents per sample
constexpr int NN = NS * NA;     // 4096 nodes
constexpr int FD = 128;         // feature dim
constexpr int ZD = 2 * FD + 2;  // 258
constexpr int FS = 16;          // feature-slice width per block
constexpr int NB = NS * (FD / FS); // 512 blocks = (sample, f-slice)
constexpr int NT = 512;         // threads per block
constexpr int XPAD = 132;       // xs row stride: 528B = 33*16 (float4-aligned), +4 bank skew
constexpr float BN_EPS = 1e-5f;
constexpr float L2E = 1.44269504088896f;
constexpr float LN2 = 0.69314718055995f;

// Stage this block's 16-feature weight slice into LDS (R3-proven, best-measured):
// wlds[k][fr] = {Wf[f][k], Wf[f][k+128], Ws[f][k], Ws[f][k+128]}, f = fq*16+fr.
// Reads: 16-row gather, L1/L2-hot (the 132KB slab is shared by 64 blocks).
// Writes: contiguous ds_write_b128 (conflict-free).
__device__ __forceinline__ void stage_w(
    float4 (*wlds)[FS], const float* __restrict__ Wf, const float* __restrict__ Ws,
    int fq, int t0, int tstep)
{
    for (int i = t0; i < FD * FS; i += tstep) {
        int k = i >> 4, fr = i & (FS - 1);
        int row = (fq * FS + fr) * ZD;
        wlds[k][fr] = make_float4(Wf[row + k], Wf[row + FD + k],
                                  Ws[row + k], Ws[row + FD + k]);
    }
}

// 8-FMA GEMM step, FMA order identical to R3/R6 (proven absmax).
#define GEMM_STEP(xv, wv) \
    aPf0 = fmaf(x0.xv, wv.x, aPf0); aQf0 = fmaf(x0.xv, wv.y, aQf0); \
    aPs0 = fmaf(x0.xv, wv.z, aPs0); aQs0 = fmaf(x0.xv, wv.w, aQs0); \
    aPf1 = fmaf(x1.xv, wv.x, aPf1); aQf1 = fmaf(x1.xv, wv.y, aQf1); \
    aPs1 = fmaf(x1.xv, wv.z, aPs1); aQs1 = fmaf(x1.xv, wv.w, aQs1);

// Fused per-(sample, f-slice) CGConv layer body. R3 structure (best measured,
// 130.9us) with the ONLY change being the R6-verified float4-xs GEMM:
// 6 ds_read_b128 per 4k-chunk (2 xs + 4 wlds) vs R3's 12 LDS instrs.
// P exp-domain -> VGPRs, Q -> 8KB LDS tile, then in-block edge aggregation +
// per-block BN partial stores (no atomics, no zeroing).
__device__ __forceinline__ void layer_body(
    const float (*xs)[XPAD], const float2* cs, float2 (*q)[FS],
    const float4 (*wlds)[FS],
    const float* __restrict__ Wf, const float* __restrict__ Ws,
    const float* __restrict__ bf, const float* __restrict__ bs,
    int tid, int s, int fq,
    float* __restrict__ agg, float* __restrict__ pS, float* __restrict__ pSS)
{
    const int fl = tid & (FS - 1);
    const int ig = tid >> 4;            // 0..31 -> nodes {ig, ig+32}
    const int f  = fq * FS + fl;
    const int base = s * NA;

    float aPf0=0.f,aQf0=0.f,aPs0=0.f,aQs0=0.f;
    float aPf1=0.f,aQf1=0.f,aPs1=0.f,aQs1=0.f;
    #pragma unroll 2
    for (int k = 0; k < FD; k += 4) {
        float4 x0 = *(const float4*)&xs[ig][k];   // 4 rows/wave, pad skews banks
        float4 x1 = *(const float4*)&xs[ig + 32][k];
        float4 w0 = wlds[k + 0][fl];              // 256B/wave, 2-way alias: free
        float4 w1 = wlds[k + 1][fl];
        float4 w2 = wlds[k + 2][fl];
        float4 w3 = wlds[k + 3][fl];
        GEMM_STEP(x, w0) GEMM_STEP(y, w1) GEMM_STEP(z, w2) GEMM_STEP(w, w3)
    }
    float we0 = Wf[f*ZD + 2*FD], we1 = Wf[f*ZD + 2*FD + 1];
    float ws0 = Ws[f*ZD + 2*FD], ws1 = Ws[f*ZD + 2*FD + 1];
    float bfv = bf[f], bsv = bs[f];
    float2 c0 = cs[ig], c1 = cs[ig + 32];
    float cf0 = c0.x*we0 + c0.y*we1, cg0 = c0.x*ws0 + c0.y*ws1;
    float cf1 = c1.x*we0 + c1.y*we1, cg1 = c1.x*ws0 + c1.y*ws1;
    float Pf0 = aPf0 + cf0 + bfv, Ps0 = aPs0 + cg0 + bsv;
    float Pf1 = aPf1 + cf1 + bfv, Ps1 = aPs1 + cg1 + bsv;
    float Qf0 = aQf0 - cf0,       Qs0 = aQs0 - cg0;
    float Qf1 = aQf1 - cf1,       Qs1 = aQs1 - cg1;
    // exp-domain: sigma = rcp(1 + e^{-P}e^{-Q}), softplus*log2e = log2(1 + e^{Ps}e^{Qs})
    float2 p0 = make_float2(__builtin_amdgcn_exp2f(-Pf0*L2E), __builtin_amdgcn_exp2f(Ps0*L2E));
    float2 p1 = make_float2(__builtin_amdgcn_exp2f(-Pf1*L2E), __builtin_amdgcn_exp2f(Ps1*L2E));
    q[ig][fl]    = make_float2(__builtin_amdgcn_exp2f(-Qf0*L2E), __builtin_amdgcn_exp2f(Qs0*L2E));
    q[ig+32][fl] = make_float2(__builtin_amdgcn_exp2f(-Qf1*L2E), __builtin_amdgcn_exp2f(Qs1*L2E));
    __syncthreads();

    // ---- edge aggregation: i in {ig, ig+32}, all 64 j, dual chains ----
    float a0=0.f, a1=0.f, b0=0.f, b1=0.f;
    #pragma unroll 4
    for (int j = 0; j < NA; j += 2) {
        float2 qa = q[j][fl];            // same-address bcast per lane-group: free
        float2 qb = q[j+1][fl];
        a0 = fmaf(__builtin_amdgcn_rcpf(1.0f + p0.x*qa.x),
                  __builtin_amdgcn_logf(1.0f + p0.y*qa.y), a0);
        b0 = fmaf(__builtin_amdgcn_rcpf(1.0f + p1.x*qa.x),
                  __builtin_amdgcn_logf(1.0f + p1.y*qa.y), b0);
        a1 = fmaf(__builtin_amdgcn_rcpf(1.0f + p0.x*qb.x),
                  __builtin_amdgcn_logf(1.0f + p0.y*qb.y), a1);
        b1 = fmaf(__builtin_amdgcn_rcpf(1.0f + p1.x*qb.x),
                  __builtin_amdgcn_logf(1.0f + p1.y*qb.y), b1);
    }
    float aA = a0 + a1, aB = b0 + b1;
    {   // remove self-loop terms (j == i)
        float2 qv0 = q[ig][fl];
        aA -= __builtin_amdgcn_rcpf(1.0f + p0.x*qv0.x) *
              __builtin_amdgcn_logf(1.0f + p0.y*qv0.y);
        float2 qv1 = q[ig+32][fl];
        aB -= __builtin_amdgcn_rcpf(1.0f + p1.x*qv1.x) *
              __builtin_amdgcn_logf(1.0f + p1.y*qv1.y);
    }
    aA *= LN2; aB *= LN2;               // log2 -> ln once, outside the sum
    agg[(base + ig) * FD + f]      = aA;
    agg[(base + ig + 32) * FD + f] = aB;

    // ---- BN partial stats: reduce 64 i per f in-block, plain stores ----
    __syncthreads();                    // all q reads done; alias as scratch
    float* sm = (float*)q;              // 2048 floats available, need 1024
    sm[tid]      = aA + aB;
    sm[NT + tid] = aA*aA + aB*aB;
    __syncthreads();
    if (tid < FS) {
        float sv = 0.f, qv = 0.f;
        #pragma unroll
        for (int r = 0; r < 32; ++r) {
            sv += sm[r * FS + tid];
            qv += sm[NT + r * FS + tid];
        }
        pS [s * FD + fq * FS + tid] = sv;   // distinct slot per block: no atomics
        pSS[s * FD + fq * FS + tid] = qv;
    }
}

// Layer 1: stage x0 tile + self-pack weight slice, fused GEMM+edge.
__global__ __launch_bounds__(NT) void layer1_kernel(
    const float* __restrict__ X0, const float* __restrict__ C,
    const float* __restrict__ Wf, const float* __restrict__ Ws,
    const float* __restrict__ bf, const float* __restrict__ bs,
    float* __restrict__ agg, float* __restrict__ pS, float* __restrict__ pSS)
{
    __shared__ __align__(16) float xs[NA][XPAD];  // 33 KB
    __shared__ float2 q[NA][FS];                  //  8 KB
    __shared__ float4 wlds[FD][FS];               // 32 KB
    __shared__ float2 cs[NA];                     // 0.5 KB (~73.5 KB -> 2 blocks/CU)
    int tid = threadIdx.x, bid = blockIdx.x;
    int s = bid & (NS - 1), fq = bid >> 6;  // 8 f-slices of a sample -> same XCD
    int base = s * NA;
    stage_w(wlds, Wf, Ws, fq, tid, NT);
    const float4* Xv = (const float4*)(X0 + base * FD);
    for (int idx = tid; idx < NA * FD / 4; idx += NT) {
        int n = idx >> 5, k4 = idx & 31;
        *(float4*)&xs[n][k4 * 4] = Xv[idx];
    }
    if (tid < NA) cs[tid] = ((const float2*)C)[base + tid];
    __syncthreads();
    layer_body(xs, cs, q, wlds, Wf, Ws, bf, bs, tid, s, fq, agg, pS, pSS);
}

// Layer 2: reduce BN1 partials (waves 0-1) || self-pack W2 slice (waves 2-7),
// then stage x1 = relu(BN1(agg1) + x0) into LDS + global, then fused layer.
__global__ __launch_bounds__(NT) void layer2_kernel(
    const float* __restrict__ X0, const float* __restrict__ agg1,
    const float* __restrict__ C,
    const float* __restrict__ pS1, const float* __restrict__ pSS1,
    const float* __restrict__ g1, const float* __restrict__ be1,
    const float* __restrict__ Wf, const float* __restrict__ Ws,
    const float* __restrict__ bf, const float* __restrict__ bs,
    float* __restrict__ x1, float* __restrict__ agg2,
    float* __restrict__ pS2, float* __restrict__ pSS2)
{
    __shared__ __align__(16) float xs[NA][XPAD];
    __shared__ float2 q[NA][FS];
    __shared__ float4 wlds[FD][FS];
    __shared__ float2 cs[NA];
    __shared__ float bnsc[FD], bnsh[FD];
    int tid = threadIdx.x, bid = blockIdx.x;
    int s = bid & (NS - 1), fq = bid >> 6;
    int base = s * NA;
    if (tid < FD) {                     // waves 0-1: reduce stats1
        float sv = 0.f, qv = 0.f;
        #pragma unroll
        for (int s2 = 0; s2 < NS; ++s2) {
            sv += pS1[s2 * FD + tid];
            qv += pSS1[s2 * FD + tid];
        }
        float m  = sv * (1.0f / NN);
        float v  = qv * (1.0f / NN) - m * m;
        float sc = g1[tid] * rsqrtf(v + BN_EPS);
        bnsc[tid] = sc;
        bnsh[tid] = be1[tid] - m * sc;
    } else {                            // waves 2-7: pack weight slice
        stage_w(wlds, Wf, Ws, fq, tid - FD, NT - FD);
        if (tid >= NT - NA) cs[tid - (NT - NA)] = ((const float2*)C)[base + tid - (NT - NA)];
    }
    __syncthreads();
    const float4* Xv  = (const float4*)(X0 + base * FD);
    const float4* Av  = (const float4*)(agg1 + base * FD);
    float4*       X1v = (float4*)(x1 + base * FD);
    for (int idx = tid; idx < NA * FD / 4; idx += NT) {
        int n = idx >> 5, k4 = (idx & 31) * 4;
        float4 x = Xv[idx], a = Av[idx];
        float4 r;
        r.x = fmaxf(fmaf(a.x, bnsc[k4 + 0], bnsh[k4 + 0]) + x.x, 0.0f);
        r.y = fmaxf(fmaf(a.y, bnsc[k4 + 1], bnsh[k4 + 1]) + x.y, 0.0f);
        r.z = fmaxf(fmaf(a.z, bnsc[k4 + 2], bnsh[k4 + 2]) + x.z, 0.0f);
        r.w = fmaxf(fmaf(a.w, bnsc[k4 + 3], bnsh[k4 + 3]) + x.w, 0.0f);
        *(float4*)&xs[n][k4] = r;
        X1v[idx] = r;                   // x1 for the epilogue kernel
    }
    __syncthreads();
    layer_body(xs, cs, q, wlds, Wf, Ws, bf, bs, tid, s, fq, agg2, pS2, pSS2);
}

// Epilogue: parallel stats2 reduce per block, out = relu(BN2(agg2) + x1).
__global__ __launch_bounds__(256) void out_kernel(
    const float4* __restrict__ x1, const float4* __restrict__ agg2,
    const float* __restrict__ pS2, const float* __restrict__ pSS2,
    const float* __restrict__ g2, const float* __restrict__ be2,
    float4* __restrict__ out)
{
    __shared__ float sm[1024];
    __shared__ float sc[FD], sh[FD];
    int tid = threadIdx.x;
    {   // 256 threads = 128 f x 2 sample-halves
        int fr = tid & (FD - 1), sq = tid >> 7;
        float sv = 0.f, qv = 0.f;
        #pragma unroll
        for (int s2 = 0; s2 < NS / 2; ++s2) {
            int si = sq * (NS / 2) + s2;
            sv += pS2[si * FD + fr];
            qv += pSS2[si * FD + fr];
        }
        sm[tid] = sv;
        sm[512 + tid] = qv;
    }
    __syncthreads();
    if (tid < FD) {
        float sv = sm[tid] + sm[FD + tid];
        float qv = sm[512 + tid] + sm[512 + FD + tid];
        float m  = sv * (1.0f / NN);
        float v  = qv * (1.0f / NN) - m * m;
        float scl = g2[tid] * rsqrtf(v + BN_EPS);
        sc[tid] = scl;
        sh[tid] = be2[tid] - m * scl;
    }
    __syncthreads();
    int idx = blockIdx.x * 256 + tid;   // < NN*FD/4
    int f0 = (idx & 31) * 4;
    float4 xv = x1[idx], av = agg2[idx];
    float4 r;
    r.x = fmaxf(fmaf(av.x, sc[f0 + 0], sh[f0 + 0]) + xv.x, 0.0f);
    r.y = fmaxf(fmaf(av.y, sc[f0 + 1], sh[f0 + 1]) + xv.y, 0.0f);
    r.z = fmaxf(fmaf(av.z, sc[f0 + 2], sh[f0 + 2]) + xv.z, 0.0f);
    r.w = fmaxf(fmaf(av.w, sc[f0 + 3], sh[f0 + 3]) + xv.w, 0.0f);
    out[idx] = r;
}

extern "C" void kernel_launch(void* const* d_in, const int* in_sizes, int n_in,
                              void* d_out, int out_size, void* d_ws, size_t ws_size,
                              hipStream_t stream) {
    const float* gnn_in  = (const float*)d_in[0];
    const float* centers = (const float*)d_in[1];
    // d_in[2]=src, d_in[3]=dst: structure known (fully connected per sample) — unused
    const float* Wf1 = (const float*)d_in[4];
    const float* bf1 = (const float*)d_in[5];
    const float* Ws1 = (const float*)d_in[6];
    const float* bs1 = (const float*)d_in[7];
    const float* g1  = (const float*)d_in[8];
    const float* be1 = (const float*)d_in[9];
    const float* Wf2 = (const float*)d_in[10];
    const float* bf2 = (const float*)d_in[11];
    const float* Ws2 = (const float*)d_in[12];
    const float* bs2 = (const float*)d_in[13];
    const float* g2  = (const float*)d_in[14];
    const float* be2 = (const float*)d_in[15];

    char* ws = (char*)d_ws;
    float* agg1  = (float*)(ws);                             // 2 MB
    float* agg2  = (float*)(ws + (2 << 20));                 // 2 MB
    float* x1    = (float*)(ws + (4 << 20));                 // 2 MB
    float* p1S   = (float*)(ws + (6 << 20));                 // 32 KB
    float* p1SS  = (float*)(ws + (6 << 20) + (32 << 10));    // 32 KB
    float* p2S   = (float*)(ws + (6 << 20) + (64 << 10));    // 32 KB
    float* p2SS  = (float*)(ws + (6 << 20) + (96 << 10));    // 32 KB

    layer1_kernel<<<NB, NT, 0, stream>>>(gnn_in, centers, Wf1, Ws1, bf1, bs1,
                                         agg1, p1S, p1SS);
    layer2_kernel<<<NB, NT, 0, stream>>>(gnn_in, agg1, centers, p1S, p1SS, g1, be1,
                                         Wf2, Ws2, bf2, bs2, x1, agg2, p2S, p2SS);
    out_kernel<<<NN * FD / 4 / 256, 256, 0, stream>>>(
        (const float4*)x1, (const float4*)agg2, p2S, p2SS, g2, be2, (float4*)d_out);
}